// Round 1
// baseline (619.982 us; speedup 1.0000x reference)
//
#include <hip/hip_runtime.h>
#include <hip/hip_bf16.h>
#include <math.h>

// Problem constants
#define BATCH 8
#define HW 16384          // 128*128
#define CIN 256           // KEY_IN == QUERY_IN
#define KCH 32            // KEY_CH
#define VCH 64            // VAL_CH
#define HEADS 8
#define DK 4
#define DV 8
#define SCALE 0.5f        // DK^-0.5

// ws layout (floats)
#define WS_KVT   0                      // [256][96]  transposed kw|vw
#define WS_QWT   (WS_KVT + 256*96)      // [256][32]  transposed qw
#define WS_KPRE  (WS_QWT + 256*32)      // [B][32][HW] k pre-softmax
#define WS_V     (WS_KPRE + BATCH*KCH*HW) // [B][64][HW]
#define WS_PART  (WS_V + BATCH*VCH*HW)  // [B][8][4chunks][40]
#define WS_CTX   (WS_PART + BATCH*HEADS*4*40) // [B][H][DV][DK] (e-major, d contiguous)
#define WS_TOTAL (WS_CTX + BATCH*HEADS*DV*DK)

// ---------------------------------------------------------------------------
// K0: transpose weights so projection inner loops read contiguous float4 rows
__global__ void transpose_w(const float* __restrict__ kw,
                            const float* __restrict__ vw,
                            const float* __restrict__ qw,
                            float* __restrict__ kvT,
                            float* __restrict__ qwT) {
    int c = threadIdx.x;            // 256 threads, 1 block
    if (c >= CIN) return;
    for (int o = 0; o < KCH; ++o) kvT[c*96 + o]      = kw[o*CIN + c];
    for (int o = 0; o < VCH; ++o) kvT[c*96 + 32 + o] = vw[o*CIN + c];
    for (int o = 0; o < KCH; ++o) qwT[c*32 + o]      = qw[o*CIN + c];
}

// ---------------------------------------------------------------------------
// K1: k & v projections. One thread per pixel, 96 fp32 accumulators.
__global__ void __launch_bounds__(256) proj_kv(const float* __restrict__ x,
                                               const float* __restrict__ kvT,
                                               const float* __restrict__ kb,
                                               const float* __restrict__ vb,
                                               float* __restrict__ kout,
                                               float* __restrict__ vout) {
    int p = blockIdx.x * 256 + threadIdx.x;     // pixel id
    int b = p >> 14;
    int n = p & (HW - 1);
    const float* xp = x + (size_t)b * CIN * HW + n;

    float ak[KCH], av[VCH];
#pragma unroll
    for (int o = 0; o < KCH; ++o) ak[o] = kb[o];
#pragma unroll
    for (int o = 0; o < VCH; ++o) av[o] = vb[o];

#pragma unroll 2
    for (int c = 0; c < CIN; ++c) {
        float xv = xp[(size_t)c * HW];
        const float4* w4 = (const float4*)(kvT + c * 96);
#pragma unroll
        for (int o4 = 0; o4 < 8; ++o4) {        // 32 k outputs
            float4 w = w4[o4];
            ak[o4*4+0] += w.x * xv;
            ak[o4*4+1] += w.y * xv;
            ak[o4*4+2] += w.z * xv;
            ak[o4*4+3] += w.w * xv;
        }
#pragma unroll
        for (int o4 = 0; o4 < 16; ++o4) {       // 64 v outputs
            float4 w = w4[8 + o4];
            av[o4*4+0] += w.x * xv;
            av[o4*4+1] += w.y * xv;
            av[o4*4+2] += w.z * xv;
            av[o4*4+3] += w.w * xv;
        }
    }

    float* kp = kout + (size_t)b * KCH * HW + n;
#pragma unroll
    for (int o = 0; o < KCH; ++o) kp[(size_t)o * HW] = ak[o];
    float* vp = vout + (size_t)b * VCH * HW + n;
#pragma unroll
    for (int o = 0; o < VCH; ++o) vp[(size_t)o * HW] = av[o];
}

// ---------------------------------------------------------------------------
// K2: context partials. grid = B*HEADS*4 chunks; block reduces its n-chunk.
// context[d][e] = sum_n softmax(k)[d,n] * v[e,n]  ->  num/den, exp w/o max
// (k values are O(1); exp is safe in fp32 and matches softmax exactly).
__global__ void __launch_bounds__(256) ctx_partial(const float* __restrict__ kpre,
                                                   const float* __restrict__ v,
                                                   float* __restrict__ part) {
    int blk = blockIdx.x;               // b*32 + h*4 + chunk
    int b  = blk >> 5;
    int h  = (blk >> 2) & 7;
    int ch = blk & 3;
    const float* kp = kpre + ((size_t)(b * KCH + h * DK)) * HW;
    const float* vp = v    + ((size_t)(b * VCH + h * DV)) * HW;

    float den[DK] = {0.f, 0.f, 0.f, 0.f};
    float num[DK][DV] = {};

    int n0 = ch * 4096 + threadIdx.x;
    for (int it = 0; it < 16; ++it) {
        int n = n0 + it * 256;
        float ek[DK];
#pragma unroll
        for (int d = 0; d < DK; ++d) ek[d] = expf(kp[(size_t)d * HW + n]);
        float vv[DV];
#pragma unroll
        for (int e = 0; e < DV; ++e) vv[e] = vp[(size_t)e * HW + n];
#pragma unroll
        for (int d = 0; d < DK; ++d) {
            den[d] += ek[d];
#pragma unroll
            for (int e = 0; e < DV; ++e) num[d][e] += ek[d] * vv[e];
        }
    }

    // block reduction of 36 values
    __shared__ float red[36][4];
    int lane = threadIdx.x & 63;
    int wv   = threadIdx.x >> 6;
#pragma unroll
    for (int i = 0; i < 36; ++i) {
        float val = (i < 4) ? den[i] : num[(i - 4) >> 3][(i - 4) & 7];
        for (int off = 32; off; off >>= 1) val += __shfl_down(val, off);
        if (lane == 0) red[i][wv] = val;
    }
    __syncthreads();
    if (threadIdx.x < 36) {
        float s = red[threadIdx.x][0] + red[threadIdx.x][1] +
                  red[threadIdx.x][2] + red[threadIdx.x][3];
        part[(size_t)blk * 40 + threadIdx.x] = s;
    }
}

// K2b: finalize context. grid = B blocks, 256 threads = (h,d,e)
__global__ void ctx_final(const float* __restrict__ part,
                          float* __restrict__ ctx) {
    int b = blockIdx.x;
    int t = threadIdx.x;                // h:3b d:2b e:3b
    int h = t >> 5, d = (t >> 3) & 3, e = t & 7;
    float num = 0.f, den = 0.f;
#pragma unroll
    for (int ch = 0; ch < 4; ++ch) {
        const float* pp = part + (size_t)(((b * 8 + h) * 4 + ch)) * 40;
        num += pp[4 + d * 8 + e];
        den += pp[d];
    }
    // store e-major with d contiguous: ctx[b][h][e][d]
    ctx[(((size_t)b * 8 + h) * 8 + e) * 4 + d] = num / den;
}

// ---------------------------------------------------------------------------
// K3: fused q-projection + q-softmax(over d) + attn combine + final conv.
__global__ void __launch_bounds__(256) fused_out(const float* __restrict__ tgt,
                                                 const float* __restrict__ qwT,
                                                 const float* __restrict__ qb,
                                                 const float* __restrict__ ctx,
                                                 const float* __restrict__ rw,
                                                 const float* __restrict__ rb,
                                                 float* __restrict__ out) {
    int p = blockIdx.x * 256 + threadIdx.x;
    int b = p >> 14;
    int n = p & (HW - 1);
    const float* tp = tgt + (size_t)b * CIN * HW + n;

    float q[KCH];
#pragma unroll
    for (int o = 0; o < KCH; ++o) q[o] = qb[o];

#pragma unroll 2
    for (int c = 0; c < CIN; ++c) {
        float xv = tp[(size_t)c * HW];
        const float4* w4 = (const float4*)(qwT + c * 32);
#pragma unroll
        for (int o4 = 0; o4 < 8; ++o4) {
            float4 w = w4[o4];
            q[o4*4+0] += w.x * xv;
            q[o4*4+1] += w.y * xv;
            q[o4*4+2] += w.z * xv;
            q[o4*4+3] += w.w * xv;
        }
    }

    // per-head softmax over d (4 vals) then attn[h*8+e] = ctx[h][e][:] . qsm
    float attn[VCH];
    const float4* cb4 = (const float4*)(ctx + (size_t)b * HEADS * DV * DK);
#pragma unroll
    for (int h = 0; h < HEADS; ++h) {
        float s0 = q[h*4+0] * SCALE, s1 = q[h*4+1] * SCALE;
        float s2 = q[h*4+2] * SCALE, s3 = q[h*4+3] * SCALE;
        float m  = fmaxf(fmaxf(s0, s1), fmaxf(s2, s3));
        float e0 = expf(s0 - m), e1 = expf(s1 - m);
        float e2 = expf(s2 - m), e3 = expf(s3 - m);
        float inv = 1.f / (e0 + e1 + e2 + e3);
        e0 *= inv; e1 *= inv; e2 *= inv; e3 *= inv;
#pragma unroll
        for (int e = 0; e < DV; ++e) {
            float4 cv = cb4[h * 8 + e];
            attn[h*8+e] = cv.x*e0 + cv.y*e1 + cv.z*e2 + cv.w*e3;
        }
    }

    // final conv: out[o] = rb[o] + rw[o][:] . attn
    float* op = out + (size_t)b * CIN * HW + n;
#pragma unroll 2
    for (int o = 0; o < 256; ++o) {
        float acc = rb[o];
        const float4* r4 = (const float4*)(rw + o * 64);
#pragma unroll
        for (int j4 = 0; j4 < 16; ++j4) {
            float4 w = r4[j4];
            acc += w.x*attn[j4*4+0] + w.y*attn[j4*4+1]
                 + w.z*attn[j4*4+2] + w.w*attn[j4*4+3];
        }
        op[(size_t)o * HW] = acc;
    }
}

// ---------------------------------------------------------------------------
extern "C" void kernel_launch(void* const* d_in, const int* in_sizes, int n_in,
                              void* d_out, int out_size, void* d_ws, size_t ws_size,
                              hipStream_t stream) {
    const float* target = (const float*)d_in[0];
    const float* input  = (const float*)d_in[1];
    const float* kw = (const float*)d_in[2];
    const float* kb = (const float*)d_in[3];
    const float* qw = (const float*)d_in[4];
    const float* qb = (const float*)d_in[5];
    const float* vw = (const float*)d_in[6];
    const float* vb = (const float*)d_in[7];
    const float* rw = (const float*)d_in[8];
    const float* rb = (const float*)d_in[9];
    float* out = (float*)d_out;
    float* ws  = (float*)d_ws;

    float* kvT  = ws + WS_KVT;
    float* qwT  = ws + WS_QWT;
    float* kpre = ws + WS_KPRE;
    float* v    = ws + WS_V;
    float* part = ws + WS_PART;
    float* ctx  = ws + WS_CTX;

    hipLaunchKernelGGL(transpose_w, dim3(1), dim3(256), 0, stream,
                       kw, vw, qw, kvT, qwT);
    hipLaunchKernelGGL(proj_kv, dim3(BATCH * HW / 256), dim3(256), 0, stream,
                       input, kvT, kb, vb, kpre, v);
    hipLaunchKernelGGL(ctx_partial, dim3(BATCH * HEADS * 4), dim3(256), 0, stream,
                       kpre, v, part);
    hipLaunchKernelGGL(ctx_final, dim3(BATCH), dim3(256), 0, stream,
                       part, ctx);
    hipLaunchKernelGGL(fused_out, dim3(BATCH * HW / 256), dim3(256), 0, stream,
                       target, qwT, qb, ctx, rw, rb, out);
}

// Round 2
// 599.132 us; speedup vs baseline: 1.0348x; 1.0348x over previous
//
#include <hip/hip_runtime.h>
#include <hip/hip_bf16.h>
#include <math.h>

// Problem constants
#define BATCH 8
#define HW 16384          // 128*128
#define CIN 256           // KEY_IN == QUERY_IN
#define KCH 32            // KEY_CH
#define VCH 64            // VAL_CH
#define HEADS 8
#define DK 4
#define DV 8
#define SCALE 0.5f        // DK^-0.5

// ws layout (float units)
#define WS_KVT   0                        // [256][96]  transposed kw|vw
#define WS_QWT   (WS_KVT + 256*96)        // [256][32]  transposed qw
#define WS_KP    (WS_QWT + 256*32)        // [B][16][HW] uint: packed bf16 pairs of exp(k)
#define WS_VP    (WS_KP + BATCH*16*HW)    // [B][32][HW] uint: packed bf16 pairs of v
#define WS_PART  (WS_VP + BATCH*32*HW)    // [B][8][16][40]
#define WS_CTX   (WS_PART + BATCH*HEADS*16*40) // [B][H][DV][DK] (e-major, d contiguous)

__device__ inline unsigned pack_bf16(float a, float b) {
    unsigned ua = __float_as_uint(a);
    unsigned ub = __float_as_uint(b);
    ua = (ua + 0x7fffu + ((ua >> 16) & 1u)) >> 16;
    ub = (ub + 0x7fffu + ((ub >> 16) & 1u)) >> 16;
    return ua | (ub << 16);
}
__device__ inline float2 unpack_bf16(unsigned u) {
    float2 r;
    r.x = __uint_as_float(u << 16);
    r.y = __uint_as_float(u & 0xffff0000u);
    return r;
}

// ---------------------------------------------------------------------------
// K0: transpose weights so projection inner loops read contiguous float4 rows
__global__ void transpose_w(const float* __restrict__ kw,
                            const float* __restrict__ vw,
                            const float* __restrict__ qw,
                            float* __restrict__ kvT,
                            float* __restrict__ qwT) {
    int c = threadIdx.x;            // 256 threads, 1 block
    if (c >= CIN) return;
    for (int o = 0; o < KCH; ++o) kvT[c*96 + o]      = kw[o*CIN + c];
    for (int o = 0; o < VCH; ++o) kvT[c*96 + 32 + o] = vw[o*CIN + c];
    for (int o = 0; o < KCH; ++o) qwT[c*32 + o]      = qw[o*CIN + c];
}

// ---------------------------------------------------------------------------
// K1: k & v projections, exp() fused for k, packed bf16 outputs.
// One thread per pixel, 96 fp32 accumulators, 16-deep load batching.
__global__ void __launch_bounds__(256) proj_kv(const float* __restrict__ x,
                                               const float* __restrict__ kvT,
                                               const float* __restrict__ kb,
                                               const float* __restrict__ vb,
                                               unsigned* __restrict__ kp_out,
                                               unsigned* __restrict__ vp_out) {
    int p = blockIdx.x * 256 + threadIdx.x;     // pixel id
    int b = p >> 14;
    int n = p & (HW - 1);
    const float* xp = x + (size_t)b * CIN * HW + n;

    float ak[KCH], av[VCH];
#pragma unroll
    for (int o = 0; o < KCH; ++o) ak[o] = kb[o];
#pragma unroll
    for (int o = 0; o < VCH; ++o) av[o] = vb[o];

    for (int c0 = 0; c0 < CIN; c0 += 16) {
        float xv[16];
#pragma unroll
        for (int j = 0; j < 16; ++j) xv[j] = xp[(size_t)(c0 + j) * HW];
#pragma unroll
        for (int j = 0; j < 16; ++j) {
            const float4* w4 = (const float4*)(kvT + (c0 + j) * 96);
            float xj = xv[j];
#pragma unroll
            for (int o4 = 0; o4 < 8; ++o4) {        // 32 k outputs
                float4 w = w4[o4];
                ak[o4*4+0] += w.x * xj;
                ak[o4*4+1] += w.y * xj;
                ak[o4*4+2] += w.z * xj;
                ak[o4*4+3] += w.w * xj;
            }
#pragma unroll
            for (int o4 = 0; o4 < 16; ++o4) {       // 64 v outputs
                float4 w = w4[8 + o4];
                av[o4*4+0] += w.x * xj;
                av[o4*4+1] += w.y * xj;
                av[o4*4+2] += w.z * xj;
                av[o4*4+3] += w.w * xj;
            }
        }
    }

    // store exp(k) as 16 packed-bf16 rows, v as 32 packed rows
    unsigned* kp = kp_out + (size_t)b * 16 * HW + n;
#pragma unroll
    for (int d = 0; d < 16; ++d)
        kp[(size_t)d * HW] = pack_bf16(expf(ak[2*d]), expf(ak[2*d+1]));
    unsigned* vp = vp_out + (size_t)b * 32 * HW + n;
#pragma unroll
    for (int e = 0; e < 32; ++e)
        vp[(size_t)e * HW] = pack_bf16(av[2*e], av[2*e+1]);
}

// ---------------------------------------------------------------------------
// K2: context partials. grid = B*HEADS*16 chunks (1024 px each).
// context[d][e] = sum_n exp(k)[d,n] * v[e,n]  (num) and sum_n exp(k)[d,n] (den)
__global__ void __launch_bounds__(256) ctx_partial(const unsigned* __restrict__ kp_in,
                                                   const unsigned* __restrict__ vp_in,
                                                   float* __restrict__ part) {
    int blk = blockIdx.x;               // ((b*8 + h)*16 + ch)
    int b  = blk >> 7;
    int h  = (blk >> 4) & 7;
    int ch = blk & 15;
    const unsigned* kp = kp_in + (size_t)b * 16 * HW + (size_t)(2*h) * HW;
    const unsigned* vp = vp_in + (size_t)b * 32 * HW + (size_t)(4*h) * HW;

    float den[DK] = {0.f, 0.f, 0.f, 0.f};
    float num[DK][DV] = {};

    int n0 = ch * 1024 + threadIdx.x;
#pragma unroll
    for (int it = 0; it < 4; ++it) {
        int n = n0 + it * 256;
        unsigned ku0 = kp[n], ku1 = kp[HW + n];
        unsigned vu0 = vp[n], vu1 = vp[HW + n];
        unsigned vu2 = vp[2*HW + n], vu3 = vp[3*HW + n];
        float2 k01 = unpack_bf16(ku0), k23 = unpack_bf16(ku1);
        float ek[DK] = {k01.x, k01.y, k23.x, k23.y};
        float2 va = unpack_bf16(vu0), vb2 = unpack_bf16(vu1);
        float2 vc = unpack_bf16(vu2), vd = unpack_bf16(vu3);
        float vv[DV] = {va.x, va.y, vb2.x, vb2.y, vc.x, vc.y, vd.x, vd.y};
#pragma unroll
        for (int d = 0; d < DK; ++d) {
            den[d] += ek[d];
#pragma unroll
            for (int e = 0; e < DV; ++e) num[d][e] += ek[d] * vv[e];
        }
    }

    // block reduction of 36 values
    __shared__ float red[36][4];
    int lane = threadIdx.x & 63;
    int wv   = threadIdx.x >> 6;
#pragma unroll
    for (int i = 0; i < 36; ++i) {
        float val = (i < 4) ? den[i] : num[(i - 4) >> 3][(i - 4) & 7];
        for (int off = 32; off; off >>= 1) val += __shfl_down(val, off);
        if (lane == 0) red[i][wv] = val;
    }
    __syncthreads();
    if (threadIdx.x < 36) {
        float s = red[threadIdx.x][0] + red[threadIdx.x][1] +
                  red[threadIdx.x][2] + red[threadIdx.x][3];
        part[(size_t)blk * 40 + threadIdx.x] = s;
    }
}

// K2b: finalize context. grid = B blocks, 256 threads = (h,d,e)
__global__ void ctx_final(const float* __restrict__ part,
                          float* __restrict__ ctx) {
    int b = blockIdx.x;
    int t = threadIdx.x;                // h:3b d:2b e:3b
    int h = t >> 5, d = (t >> 3) & 3, e = t & 7;
    float num = 0.f, den = 0.f;
#pragma unroll
    for (int ch = 0; ch < 16; ++ch) {
        const float* pp = part + (size_t)(((b * 8 + h) * 16 + ch)) * 40;
        num += pp[4 + d * 8 + e];
        den += pp[d];
    }
    // store e-major with d contiguous: ctx[b][h][e][d]
    ctx[(((size_t)b * 8 + h) * 8 + e) * 4 + d] = num / den;
}

// ---------------------------------------------------------------------------
// K3: fused q-projection + q-softmax(over d) + attn combine + final conv.
__global__ void __launch_bounds__(256) fused_out(const float* __restrict__ tgt,
                                                 const float* __restrict__ qwT,
                                                 const float* __restrict__ qb,
                                                 const float* __restrict__ ctx,
                                                 const float* __restrict__ rw,
                                                 const float* __restrict__ rb,
                                                 float* __restrict__ out) {
    int p = blockIdx.x * 256 + threadIdx.x;
    int b = p >> 14;
    int n = p & (HW - 1);
    const float* tp = tgt + (size_t)b * CIN * HW + n;

    float q[KCH];
#pragma unroll
    for (int o = 0; o < KCH; ++o) q[o] = qb[o];

    for (int c0 = 0; c0 < CIN; c0 += 16) {
        float xv[16];
#pragma unroll
        for (int j = 0; j < 16; ++j) xv[j] = tp[(size_t)(c0 + j) * HW];
#pragma unroll
        for (int j = 0; j < 16; ++j) {
            const float4* w4 = (const float4*)(qwT + (c0 + j) * 32);
            float xj = xv[j];
#pragma unroll
            for (int o4 = 0; o4 < 8; ++o4) {
                float4 w = w4[o4];
                q[o4*4+0] += w.x * xj;
                q[o4*4+1] += w.y * xj;
                q[o4*4+2] += w.z * xj;
                q[o4*4+3] += w.w * xj;
            }
        }
    }

    // per-head softmax over d (4 vals) then attn[h*8+e] = ctx[h][e][:] . qsm
    float attn[VCH];
    const float4* cb4 = (const float4*)(ctx + (size_t)b * HEADS * DV * DK);
#pragma unroll
    for (int h = 0; h < HEADS; ++h) {
        float s0 = q[h*4+0] * SCALE, s1 = q[h*4+1] * SCALE;
        float s2 = q[h*4+2] * SCALE, s3 = q[h*4+3] * SCALE;
        float m  = fmaxf(fmaxf(s0, s1), fmaxf(s2, s3));
        float e0 = expf(s0 - m), e1 = expf(s1 - m);
        float e2 = expf(s2 - m), e3 = expf(s3 - m);
        float inv = 1.f / (e0 + e1 + e2 + e3);
        e0 *= inv; e1 *= inv; e2 *= inv; e3 *= inv;
#pragma unroll
        for (int e = 0; e < DV; ++e) {
            float4 cv = cb4[h * 8 + e];
            attn[h*8+e] = cv.x*e0 + cv.y*e1 + cv.z*e2 + cv.w*e3;
        }
    }

    // final conv: out[o] = rb[o] + rw[o][:] . attn
    float* op = out + (size_t)b * CIN * HW + n;
#pragma unroll 4
    for (int o = 0; o < 256; ++o) {
        float acc = rb[o];
        const float4* r4 = (const float4*)(rw + o * 64);
#pragma unroll
        for (int j4 = 0; j4 < 16; ++j4) {
            float4 w = r4[j4];
            acc += w.x*attn[j4*4+0] + w.y*attn[j4*4+1]
                 + w.z*attn[j4*4+2] + w.w*attn[j4*4+3];
        }
        op[(size_t)o * HW] = acc;
    }
}

// ---------------------------------------------------------------------------
extern "C" void kernel_launch(void* const* d_in, const int* in_sizes, int n_in,
                              void* d_out, int out_size, void* d_ws, size_t ws_size,
                              hipStream_t stream) {
    const float* target = (const float*)d_in[0];
    const float* input  = (const float*)d_in[1];
    const float* kw = (const float*)d_in[2];
    const float* kb = (const float*)d_in[3];
    const float* qw = (const float*)d_in[4];
    const float* qb = (const float*)d_in[5];
    const float* vw = (const float*)d_in[6];
    const float* vb = (const float*)d_in[7];
    const float* rw = (const float*)d_in[8];
    const float* rb = (const float*)d_in[9];
    float* out = (float*)d_out;
    float* ws  = (float*)d_ws;

    float*    kvT  = ws + WS_KVT;
    float*    qwT  = ws + WS_QWT;
    unsigned* kp   = (unsigned*)(ws + WS_KP);
    unsigned* vp   = (unsigned*)(ws + WS_VP);
    float*    part = ws + WS_PART;
    float*    ctx  = ws + WS_CTX;

    hipLaunchKernelGGL(transpose_w, dim3(1), dim3(256), 0, stream,
                       kw, vw, qw, kvT, qwT);
    hipLaunchKernelGGL(proj_kv, dim3(BATCH * HW / 256), dim3(256), 0, stream,
                       input, kvT, kb, vb, kp, vp);
    hipLaunchKernelGGL(ctx_partial, dim3(BATCH * HEADS * 16), dim3(256), 0, stream,
                       kp, vp, part);
    hipLaunchKernelGGL(ctx_final, dim3(BATCH), dim3(256), 0, stream,
                       part, ctx);
    hipLaunchKernelGGL(fused_out, dim3(BATCH * HW / 256), dim3(256), 0, stream,
                       target, qwT, qb, ctx, rw, rb, out);
}

// Round 3
// 559.344 us; speedup vs baseline: 1.1084x; 1.0711x over previous
//
#include <hip/hip_runtime.h>
#include <hip/hip_bf16.h>
#include <math.h>

// Problem constants
#define BATCH 8
#define HW 16384          // 128*128
#define CIN 256           // KEY_IN == QUERY_IN
#define KCH 32            // KEY_CH
#define VCH 64            // VAL_CH
#define HEADS 8
#define DK 4
#define DV 8
#define SCALE 0.5f        // DK^-0.5

// ws layout (float units)
#define WS_KVT   0                        // [256][96]  transposed kw|vw
#define WS_QWT   (WS_KVT + 256*96)        // [256][32]  transposed qw
#define WS_KP    (WS_QWT + 256*32)        // [B][16][HW] uint: packed bf16 pairs of exp(k)
#define WS_VP    (WS_KP + BATCH*16*HW)    // [B][32][HW] uint: packed bf16 pairs of v
#define WS_PART  (WS_VP + BATCH*32*HW)    // [B][8][16][40]
#define WS_CTX   (WS_PART + BATCH*HEADS*16*40) // [B][H][DV][DK] (e-major, d contiguous)

__device__ inline unsigned pack_bf16(float a, float b) {
    unsigned ua = __float_as_uint(a);
    unsigned ub = __float_as_uint(b);
    ua = (ua + 0x7fffu + ((ua >> 16) & 1u)) >> 16;
    ub = (ub + 0x7fffu + ((ub >> 16) & 1u)) >> 16;
    return ua | (ub << 16);
}
__device__ inline float2 unpack_bf16(unsigned u) {
    float2 r;
    r.x = __uint_as_float(u << 16);
    r.y = __uint_as_float(u & 0xffff0000u);
    return r;
}

// ---------------------------------------------------------------------------
// K0: transpose weights so inner loops read contiguous float4 rows
__global__ void transpose_w(const float* __restrict__ kw,
                            const float* __restrict__ vw,
                            const float* __restrict__ qw,
                            float* __restrict__ kvT,
                            float* __restrict__ qwT) {
    int c = threadIdx.x;            // 256 threads, 1 block
    if (c >= CIN) return;
    for (int o = 0; o < KCH; ++o) kvT[c*96 + o]      = kw[o*CIN + c];
    for (int o = 0; o < VCH; ++o) kvT[c*96 + 32 + o] = vw[o*CIN + c];
    for (int o = 0; o < KCH; ++o) qwT[c*32 + o]      = qw[o*CIN + c];
}

// ---------------------------------------------------------------------------
// K1: k & v projections, exp() fused for k, packed bf16 outputs.
// Weights staged in LDS (96 KB) -> broadcast ds_read_b128, no VMEM thrash.
__global__ void __launch_bounds__(512) proj_kv(const float* __restrict__ x,
                                               const float* __restrict__ kvT,
                                               const float* __restrict__ kb,
                                               const float* __restrict__ vb,
                                               unsigned* __restrict__ kp_out,
                                               unsigned* __restrict__ vp_out) {
    __shared__ float wlds[256 * 96];          // 96 KB
    {
        const float4* s = (const float4*)kvT;
        float4* d = (float4*)wlds;
        for (int i = threadIdx.x; i < 256 * 96 / 4; i += 512) d[i] = s[i];
    }
    __syncthreads();

    int p = blockIdx.x * 512 + threadIdx.x;   // pixel id
    int b = p >> 14;
    int n = p & (HW - 1);
    const float* xp = x + (size_t)b * CIN * HW + n;

    float ak[KCH], av[VCH];
#pragma unroll
    for (int o = 0; o < KCH; ++o) ak[o] = kb[o];
#pragma unroll
    for (int o = 0; o < VCH; ++o) av[o] = vb[o];

    for (int c0 = 0; c0 < CIN; c0 += 16) {
        float xv[16];
#pragma unroll
        for (int j = 0; j < 16; ++j) xv[j] = xp[(size_t)(c0 + j) * HW];
#pragma unroll
        for (int j = 0; j < 16; ++j) {
            const float4* w4 = (const float4*)(wlds + (c0 + j) * 96);
            float xj = xv[j];
#pragma unroll
            for (int o4 = 0; o4 < 8; ++o4) {        // 32 k outputs
                float4 w = w4[o4];
                ak[o4*4+0] += w.x * xj;
                ak[o4*4+1] += w.y * xj;
                ak[o4*4+2] += w.z * xj;
                ak[o4*4+3] += w.w * xj;
            }
#pragma unroll
            for (int o4 = 0; o4 < 16; ++o4) {       // 64 v outputs
                float4 w = w4[8 + o4];
                av[o4*4+0] += w.x * xj;
                av[o4*4+1] += w.y * xj;
                av[o4*4+2] += w.z * xj;
                av[o4*4+3] += w.w * xj;
            }
        }
    }

    unsigned* kp = kp_out + (size_t)b * 16 * HW + n;
#pragma unroll
    for (int d = 0; d < 16; ++d)
        kp[(size_t)d * HW] = pack_bf16(expf(ak[2*d]), expf(ak[2*d+1]));
    unsigned* vp = vp_out + (size_t)b * 32 * HW + n;
#pragma unroll
    for (int e = 0; e < 32; ++e)
        vp[(size_t)e * HW] = pack_bf16(av[2*e], av[2*e+1]);
}

// ---------------------------------------------------------------------------
// K2: context partials. grid = B*HEADS*16 chunks (1024 px each).
__global__ void __launch_bounds__(256) ctx_partial(const unsigned* __restrict__ kp_in,
                                                   const unsigned* __restrict__ vp_in,
                                                   float* __restrict__ part) {
    int blk = blockIdx.x;               // ((b*8 + h)*16 + ch)
    int b  = blk >> 7;
    int h  = (blk >> 4) & 7;
    int ch = blk & 15;
    const unsigned* kp = kp_in + (size_t)b * 16 * HW + (size_t)(2*h) * HW;
    const unsigned* vp = vp_in + (size_t)b * 32 * HW + (size_t)(4*h) * HW;

    float den[DK] = {0.f, 0.f, 0.f, 0.f};
    float num[DK][DV] = {};

    int n0 = ch * 1024 + threadIdx.x;
#pragma unroll
    for (int it = 0; it < 4; ++it) {
        int n = n0 + it * 256;
        unsigned ku0 = kp[n], ku1 = kp[HW + n];
        unsigned vu0 = vp[n], vu1 = vp[HW + n];
        unsigned vu2 = vp[2*HW + n], vu3 = vp[3*HW + n];
        float2 k01 = unpack_bf16(ku0), k23 = unpack_bf16(ku1);
        float ek[DK] = {k01.x, k01.y, k23.x, k23.y};
        float2 va = unpack_bf16(vu0), vb2 = unpack_bf16(vu1);
        float2 vc = unpack_bf16(vu2), vd = unpack_bf16(vu3);
        float vv[DV] = {va.x, va.y, vb2.x, vb2.y, vc.x, vc.y, vd.x, vd.y};
#pragma unroll
        for (int d = 0; d < DK; ++d) {
            den[d] += ek[d];
#pragma unroll
            for (int e = 0; e < DV; ++e) num[d][e] += ek[d] * vv[e];
        }
    }

    __shared__ float red[36][4];
    int lane = threadIdx.x & 63;
    int wv   = threadIdx.x >> 6;
#pragma unroll
    for (int i = 0; i < 36; ++i) {
        float val = (i < 4) ? den[i] : num[(i - 4) >> 3][(i - 4) & 7];
        for (int off = 32; off; off >>= 1) val += __shfl_down(val, off);
        if (lane == 0) red[i][wv] = val;
    }
    __syncthreads();
    if (threadIdx.x < 36) {
        float s = red[threadIdx.x][0] + red[threadIdx.x][1] +
                  red[threadIdx.x][2] + red[threadIdx.x][3];
        part[(size_t)blk * 40 + threadIdx.x] = s;
    }
}

// K2b: finalize context. grid = B blocks, 256 threads = (h,d,e)
__global__ void ctx_final(const float* __restrict__ part,
                          float* __restrict__ ctx) {
    int b = blockIdx.x;
    int t = threadIdx.x;                // h:3b d:2b e:3b
    int h = t >> 5, d = (t >> 3) & 3, e = t & 7;
    float num = 0.f, den = 0.f;
#pragma unroll
    for (int ch = 0; ch < 16; ++ch) {
        const float* pp = part + (size_t)(((b * 8 + h) * 16 + ch)) * 40;
        num += pp[4 + d * 8 + e];
        den += pp[d];
    }
    ctx[(((size_t)b * 8 + h) * 8 + e) * 4 + d] = num / den;
}

// ---------------------------------------------------------------------------
// K3: fused q-projection + q-softmax + attn combine + final conv.
// qw (32 KB) + rw (64 KB) + ctx + rb staged in LDS; all weight reads are
// LDS broadcasts; global traffic = read target once + write out once.
__global__ void __launch_bounds__(512) fused_out(const float* __restrict__ tgt,
                                                 const float* __restrict__ qwT,
                                                 const float* __restrict__ qb,
                                                 const float* __restrict__ ctx,
                                                 const float* __restrict__ rw,
                                                 const float* __restrict__ rb,
                                                 float* __restrict__ out) {
    __shared__ float qwlds[256 * 32];   // 32 KB
    __shared__ float rwlds[256 * 64];   // 64 KB
    __shared__ float ctxlds[256];       // 1 KB
    __shared__ float rblds[256];        // 1 KB

    int b = blockIdx.x >> 5;            // 32 blocks per batch
    {
        const float4* s = (const float4*)qwT;
        float4* d = (float4*)qwlds;
        for (int i = threadIdx.x; i < 2048; i += 512) d[i] = s[i];
    }
    {
        const float4* s = (const float4*)rw;
        float4* d = (float4*)rwlds;
        for (int i = threadIdx.x; i < 4096; i += 512) d[i] = s[i];
    }
    if (threadIdx.x < 64)
        ((float4*)ctxlds)[threadIdx.x] =
            ((const float4*)(ctx + (size_t)b * 256))[threadIdx.x];
    if (threadIdx.x >= 64 && threadIdx.x < 128)
        ((float4*)rblds)[threadIdx.x - 64] = ((const float4*)rb)[threadIdx.x - 64];
    __syncthreads();

    int p = blockIdx.x * 512 + threadIdx.x;
    int n = p & (HW - 1);
    const float* tp = tgt + (size_t)b * CIN * HW + n;

    float q[KCH];
#pragma unroll
    for (int o = 0; o < KCH; ++o) q[o] = qb[o];

    for (int c0 = 0; c0 < CIN; c0 += 16) {
        float xv[16];
#pragma unroll
        for (int j = 0; j < 16; ++j) xv[j] = tp[(size_t)(c0 + j) * HW];
#pragma unroll
        for (int j = 0; j < 16; ++j) {
            const float4* w4 = (const float4*)(qwlds + (c0 + j) * 32);
            float xj = xv[j];
#pragma unroll
            for (int o4 = 0; o4 < 8; ++o4) {
                float4 w = w4[o4];
                q[o4*4+0] += w.x * xj;
                q[o4*4+1] += w.y * xj;
                q[o4*4+2] += w.z * xj;
                q[o4*4+3] += w.w * xj;
            }
        }
    }

    // per-head softmax over d (4 vals) then attn[h*8+e] = ctx[h][e][:] . qsm
    float attn[VCH];
    const float4* cb4 = (const float4*)ctxlds;
#pragma unroll
    for (int h = 0; h < HEADS; ++h) {
        float s0 = q[h*4+0] * SCALE, s1 = q[h*4+1] * SCALE;
        float s2 = q[h*4+2] * SCALE, s3 = q[h*4+3] * SCALE;
        float m  = fmaxf(fmaxf(s0, s1), fmaxf(s2, s3));
        float e0 = expf(s0 - m), e1 = expf(s1 - m);
        float e2 = expf(s2 - m), e3 = expf(s3 - m);
        float inv = 1.f / (e0 + e1 + e2 + e3);
        e0 *= inv; e1 *= inv; e2 *= inv; e3 *= inv;
#pragma unroll
        for (int e = 0; e < DV; ++e) {
            float4 cv = cb4[h * 8 + e];
            attn[h*8+e] = cv.x*e0 + cv.y*e1 + cv.z*e2 + cv.w*e3;
        }
    }

    // final conv from LDS: out[o] = rb[o] + rw[o][:] . attn
    float* op = out + (size_t)b * CIN * HW + n;
#pragma unroll 2
    for (int o = 0; o < 256; ++o) {
        float acc = rblds[o];
        const float4* r4 = (const float4*)(rwlds + o * 64);
#pragma unroll
        for (int j4 = 0; j4 < 16; ++j4) {
            float4 w = r4[j4];
            acc += w.x*attn[j4*4+0] + w.y*attn[j4*4+1]
                 + w.z*attn[j4*4+2] + w.w*attn[j4*4+3];
        }
        op[(size_t)o * HW] = acc;
    }
}

// ---------------------------------------------------------------------------
extern "C" void kernel_launch(void* const* d_in, const int* in_sizes, int n_in,
                              void* d_out, int out_size, void* d_ws, size_t ws_size,
                              hipStream_t stream) {
    const float* target = (const float*)d_in[0];
    const float* input  = (const float*)d_in[1];
    const float* kw = (const float*)d_in[2];
    const float* kb = (const float*)d_in[3];
    const float* qw = (const float*)d_in[4];
    const float* qb = (const float*)d_in[5];
    const float* vw = (const float*)d_in[6];
    const float* vb = (const float*)d_in[7];
    const float* rw = (const float*)d_in[8];
    const float* rb = (const float*)d_in[9];
    float* out = (float*)d_out;
    float* ws  = (float*)d_ws;

    float*    kvT  = ws + WS_KVT;
    float*    qwT  = ws + WS_QWT;
    unsigned* kp   = (unsigned*)(ws + WS_KP);
    unsigned* vp   = (unsigned*)(ws + WS_VP);
    float*    part = ws + WS_PART;
    float*    ctx  = ws + WS_CTX;

    hipLaunchKernelGGL(transpose_w, dim3(1), dim3(256), 0, stream,
                       kw, vw, qw, kvT, qwT);
    hipLaunchKernelGGL(proj_kv, dim3(BATCH * HW / 512), dim3(512), 0, stream,
                       input, kvT, kb, vb, kp, vp);
    hipLaunchKernelGGL(ctx_partial, dim3(BATCH * HEADS * 16), dim3(256), 0, stream,
                       kp, vp, part);
    hipLaunchKernelGGL(ctx_final, dim3(BATCH), dim3(256), 0, stream,
                       part, ctx);
    hipLaunchKernelGGL(fused_out, dim3(BATCH * HW / 512), dim3(512), 0, stream,
                       target, qwT, qb, ctx, rw, rb, out);
}

// Round 5
// 126.337 us; speedup vs baseline: 4.9074x; 4.4274x over previous
//
#include <hip/hip_runtime.h>
#include <hip/hip_bf16.h>
#include <math.h>

// Problem constants
#define BATCH 8
#define HW 16384          // 128*128
#define CIN 256           // KEY_IN == QUERY_IN
#define KCH 32            // KEY_CH
#define VCH 64            // VAL_CH
#define HEADS 8
#define DK 4
#define DV 8
#define SCALE 0.5f        // DK^-0.5

typedef _Float16 f16;
typedef f16 f16x8 __attribute__((ext_vector_type(8)));
typedef float f32x4 __attribute__((ext_vector_type(4)));

// ws layout (float units)
#define WS_WKVF 0                         // [6mt][8kc][64lane][8j] f16 (kw rows 0-31, vw rows 32-95)
#define WS_QWF  12288                     // [2mt][8kc][64][8] f16
#define WS_RWF  16384                     // [16mt][2kc][64][8] f16
#define WS_KP   24576                     // [B][16][HW] uint: packed bf16 pairs of exp(k)
#define WS_VP   (WS_KP + BATCH*16*HW)     // [B][32][HW] uint: packed bf16 pairs of v
#define WS_PART (WS_VP + BATCH*32*HW)     // [B][8][16][40]
#define WS_CTX  (WS_PART + BATCH*HEADS*16*40) // [B][H][DV][DK] (e-major, d contiguous)

__device__ inline unsigned pack_bf16(float a, float b) {
    unsigned ua = __float_as_uint(a);
    unsigned ub = __float_as_uint(b);
    ua = (ua + 0x7fffu + ((ua >> 16) & 1u)) >> 16;
    ub = (ub + 0x7fffu + ((ub >> 16) & 1u)) >> 16;
    return ua | (ub << 16);
}
__device__ inline float2 unpack_bf16(unsigned u) {
    float2 r;
    r.x = __uint_as_float(u << 16);
    r.y = __uint_as_float(u & 0xffff0000u);
    return r;
}
// pack two fp32 -> one dword holding 2 f16 (round-toward-zero pk cvt)
__device__ inline unsigned pk_f16(float a, float b) {
    auto h = __builtin_amdgcn_cvt_pkrtz(a, b);   // __fp16 ext_vector(2)
    union { decltype(h) v; unsigned u; } c;
    c.v = h;
    return c.u;
}

// ---------------------------------------------------------------------------
// K0: pre-pack all weight matrices into per-lane MFMA A-fragment order (f16).
// A-frag (16x16x32): lane l holds A[row = mt*16 + (l&15)][k = kc*32 + (l>>4)*8 + j]
__global__ void prepack(const float* __restrict__ kw, const float* __restrict__ vw,
                        const float* __restrict__ qw, const float* __restrict__ rw,
                        f16* __restrict__ wkvf, f16* __restrict__ qwf, f16* __restrict__ rwf) {
    int t = blockIdx.x * 256 + threadIdx.x;
    int stride = gridDim.x * 256;
    for (int i = t; i < 6*8*64*8; i += stride) {       // kv weights, M=96
        int j = i & 7, lane = (i >> 3) & 63, kc = (i >> 9) & 7, mt = i >> 12;
        int row = mt*16 + (lane & 15);
        int k = kc*32 + (lane >> 4)*8 + j;
        float v = row < 32 ? kw[row*CIN + k] : vw[(row-32)*CIN + k];
        wkvf[i] = (f16)v;
    }
    for (int i = t; i < 2*8*64*8; i += stride) {       // q weights, M=32
        int j = i & 7, lane = (i >> 3) & 63, kc = (i >> 9) & 7, mt = i >> 12;
        int row = mt*16 + (lane & 15);
        int k = kc*32 + (lane >> 4)*8 + j;
        qwf[i] = (f16)qw[row*CIN + k];
    }
    for (int i = t; i < 16*2*64*8; i += stride) {      // rw, M=256, K=64
        int j = i & 7, lane = (i >> 3) & 63, kc2 = (i >> 9) & 1, mt = i >> 10;
        int row = mt*16 + (lane & 15);
        int e = kc2*32 + (lane >> 4)*8 + j;
        rwf[i] = (f16)rw[row*VCH + e];
    }
}

// ---------------------------------------------------------------------------
// K1: k & v projections via f16 MFMA. Block = 4 waves (2 M x 2 N), tile 96x128.
// No LDS, no barriers: A-frags from pre-packed global (L2-hot), B per-lane direct.
__global__ void __launch_bounds__(256) proj_kv_mfma(const float* __restrict__ x,
    const f16* __restrict__ wkvf, const float* __restrict__ kb_,
    const float* __restrict__ vb_, unsigned* __restrict__ kp_out,
    unsigned* __restrict__ vp_out) {
    int b    = blockIdx.x >> 7;
    int bpx  = (blockIdx.x & 127) * 128;
    int wave = threadIdx.x >> 6, lane = threadIdx.x & 63;
    int wm = wave >> 1, wn = wave & 1;
    int col = lane & 15, kb = lane >> 4;
    int px0 = bpx + wn * 64;
    const float* Xb = x + (size_t)b * CIN * HW;

    f32x4 acc[3][4];
#pragma unroll
    for (int m = 0; m < 3; ++m)
#pragma unroll
        for (int n = 0; n < 4; ++n) acc[m][n] = (f32x4){0.f, 0.f, 0.f, 0.f};

    for (int kc = 0; kc < 8; ++kc) {
        f16x8 afr[3];
#pragma unroll
        for (int mt = 0; mt < 3; ++mt)
            afr[mt] = *(const f16x8*)(wkvf + (size_t)(((wm*3 + mt)*8 + kc)*64 + lane)*8);
        float xb[4][8];
#pragma unroll
        for (int nt = 0; nt < 4; ++nt)
#pragma unroll
            for (int j = 0; j < 8; ++j)
                xb[nt][j] = Xb[(size_t)(kc*32 + kb*8 + j)*HW + px0 + nt*16 + col];
        f16x8 bfr[4];
#pragma unroll
        for (int nt = 0; nt < 4; ++nt) {
            union { f16x8 v; unsigned u[4]; } u;
#pragma unroll
            for (int p = 0; p < 4; ++p)
                u.u[p] = pk_f16(xb[nt][2*p], xb[nt][2*p+1]);
            bfr[nt] = u.v;
        }
#pragma unroll
        for (int mt = 0; mt < 3; ++mt)
#pragma unroll
            for (int nt = 0; nt < 4; ++nt)
                acc[mt][nt] = __builtin_amdgcn_mfma_f32_16x16x32_f16(
                    afr[mt], bfr[nt], acc[mt][nt], 0, 0, 0);
    }

    // epilogue: D row = kb*4 + r, col = lane&15
#pragma unroll
    for (int mt = 0; mt < 3; ++mt) {
        int row0 = wm*48 + mt*16 + kb*4;      // global output channel of r=0
        bool isk = row0 < 32;
        float4 bias = isk ? *(const float4*)(kb_ + row0)
                          : *(const float4*)(vb_ + row0 - 32);
#pragma unroll
        for (int nt = 0; nt < 4; ++nt) {
            int px = px0 + nt*16 + col;
            float v0 = acc[mt][nt][0] + bias.x;
            float v1 = acc[mt][nt][1] + bias.y;
            float v2 = acc[mt][nt][2] + bias.z;
            float v3 = acc[mt][nt][3] + bias.w;
            if (isk) {
                unsigned* kp = kp_out + (size_t)(b*16 + (row0 >> 1))*HW + px;
                kp[0]  = pack_bf16(expf(v0), expf(v1));
                kp[HW] = pack_bf16(expf(v2), expf(v3));
            } else {
                int vr = row0 - 32;
                unsigned* vp = vp_out + (size_t)(b*32 + (vr >> 1))*HW + px;
                vp[0]  = pack_bf16(v0, v1);
                vp[HW] = pack_bf16(v2, v3);
            }
        }
    }
}

// ---------------------------------------------------------------------------
// K2: context partials. grid = B*HEADS*16 chunks (1024 px each). (unchanged)
__global__ void __launch_bounds__(256) ctx_partial(const unsigned* __restrict__ kp_in,
                                                   const unsigned* __restrict__ vp_in,
                                                   float* __restrict__ part) {
    int blk = blockIdx.x;               // ((b*8 + h)*16 + ch)
    int b  = blk >> 7;
    int h  = (blk >> 4) & 7;
    int ch = blk & 15;
    const unsigned* kp = kp_in + (size_t)b * 16 * HW + (size_t)(2*h) * HW;
    const unsigned* vp = vp_in + (size_t)b * 32 * HW + (size_t)(4*h) * HW;

    float den[DK] = {0.f, 0.f, 0.f, 0.f};
    float num[DK][DV] = {};

    int n0 = ch * 1024 + threadIdx.x;
#pragma unroll
    for (int it = 0; it < 4; ++it) {
        int n = n0 + it * 256;
        unsigned ku0 = kp[n], ku1 = kp[HW + n];
        unsigned vu0 = vp[n], vu1 = vp[HW + n];
        unsigned vu2 = vp[2*HW + n], vu3 = vp[3*HW + n];
        float2 k01 = unpack_bf16(ku0), k23 = unpack_bf16(ku1);
        float ek[DK] = {k01.x, k01.y, k23.x, k23.y};
        float2 va = unpack_bf16(vu0), vb2 = unpack_bf16(vu1);
        float2 vc = unpack_bf16(vu2), vd = unpack_bf16(vu3);
        float vv[DV] = {va.x, va.y, vb2.x, vb2.y, vc.x, vc.y, vd.x, vd.y};
#pragma unroll
        for (int d = 0; d < DK; ++d) {
            den[d] += ek[d];
#pragma unroll
            for (int e = 0; e < DV; ++e) num[d][e] += ek[d] * vv[e];
        }
    }

    __shared__ float red[36][4];
    int lane = threadIdx.x & 63;
    int wv   = threadIdx.x >> 6;
#pragma unroll
    for (int i = 0; i < 36; ++i) {
        float val = (i < 4) ? den[i] : num[(i - 4) >> 3][(i - 4) & 7];
        for (int off = 32; off; off >>= 1) val += __shfl_down(val, off);
        if (lane == 0) red[i][wv] = val;
    }
    __syncthreads();
    if (threadIdx.x < 36) {
        float s = red[threadIdx.x][0] + red[threadIdx.x][1] +
                  red[threadIdx.x][2] + red[threadIdx.x][3];
        part[(size_t)blk * 40 + threadIdx.x] = s;
    }
}

// K2b: finalize context. grid = B blocks, 256 threads = (h,d,e) (unchanged)
__global__ void ctx_final(const float* __restrict__ part,
                          float* __restrict__ ctx) {
    int b = blockIdx.x;
    int t = threadIdx.x;                // h:3b d:2b e:3b
    int h = t >> 5, d = (t >> 3) & 3, e = t & 7;
    float num = 0.f, den = 0.f;
#pragma unroll
    for (int ch = 0; ch < 16; ++ch) {
        const float* pp = part + (size_t)(((b * 8 + h) * 16 + ch)) * 40;
        num += pp[4 + d * 8 + e];
        den += pp[d];
    }
    ctx[(((size_t)b * 8 + h) * 8 + e) * 4 + d] = num / den;
}

// ---------------------------------------------------------------------------
// K3: fused q-proj (MFMA) + in-lane q-softmax + attn combine + final conv (MFMA).
// Head h = mt2*4 + (lane>>4): the 4 softmax channels are the lane's 4 acc regs;
// attn rows h*8..h*8+7 are exactly the B-fragment this lane feeds to GEMM2.
__global__ void __launch_bounds__(256) fused_mfma(const float* __restrict__ tgt,
    const f16* __restrict__ qwf, const float* __restrict__ qb_,
    const float* __restrict__ ctx, const f16* __restrict__ rwf,
    const float* __restrict__ rb_, float* __restrict__ out) {
    int b    = blockIdx.x >> 6;
    int bpx  = (blockIdx.x & 63) * 256;
    int wave = threadIdx.x >> 6, lane = threadIdx.x & 63;
    int col = lane & 15, kb = lane >> 4;
    int px0 = bpx + wave * 64;
    const float* Tb = tgt + (size_t)b * CIN * HW;

    // GEMM1: q[32][64px]
    f32x4 qacc[2][4];
#pragma unroll
    for (int m = 0; m < 2; ++m)
#pragma unroll
        for (int n = 0; n < 4; ++n) qacc[m][n] = (f32x4){0.f, 0.f, 0.f, 0.f};

    for (int kc = 0; kc < 8; ++kc) {
        f16x8 afr[2];
#pragma unroll
        for (int mt = 0; mt < 2; ++mt)
            afr[mt] = *(const f16x8*)(qwf + (size_t)((mt*8 + kc)*64 + lane)*8);
        float xb[4][8];
#pragma unroll
        for (int nt = 0; nt < 4; ++nt)
#pragma unroll
            for (int j = 0; j < 8; ++j)
                xb[nt][j] = Tb[(size_t)(kc*32 + kb*8 + j)*HW + px0 + nt*16 + col];
        f16x8 bfr[4];
#pragma unroll
        for (int nt = 0; nt < 4; ++nt) {
            union { f16x8 v; unsigned u[4]; } u;
#pragma unroll
            for (int p = 0; p < 4; ++p)
                u.u[p] = pk_f16(xb[nt][2*p], xb[nt][2*p+1]);
            bfr[nt] = u.v;
        }
#pragma unroll
        for (int mt = 0; mt < 2; ++mt)
#pragma unroll
            for (int nt = 0; nt < 4; ++nt)
                qacc[mt][nt] = __builtin_amdgcn_mfma_f32_16x16x32_f16(
                    afr[mt], bfr[nt], qacc[mt][nt], 0, 0, 0);
    }

    // in-lane softmax over the 4 head channels + combine with ctx -> attn f16
    unsigned attnu[2][4][4];            // [kc2][nt][f16-pair]
#pragma unroll
    for (int mt2 = 0; mt2 < 2; ++mt2) {
        int h = mt2*4 + kb;
        float4 qb4 = *(const float4*)(qb_ + mt2*16 + kb*4);
        float4 cx[8];
#pragma unroll
        for (int e = 0; e < 8; ++e)
            cx[e] = *(const float4*)(ctx + (size_t)((b*8 + h)*8 + e)*4);
#pragma unroll
        for (int nt = 0; nt < 4; ++nt) {
            float s0 = (qacc[mt2][nt][0] + qb4.x) * SCALE;
            float s1 = (qacc[mt2][nt][1] + qb4.y) * SCALE;
            float s2 = (qacc[mt2][nt][2] + qb4.z) * SCALE;
            float s3 = (qacc[mt2][nt][3] + qb4.w) * SCALE;
            float m  = fmaxf(fmaxf(s0, s1), fmaxf(s2, s3));
            float e0 = expf(s0 - m), e1 = expf(s1 - m);
            float e2 = expf(s2 - m), e3 = expf(s3 - m);
            float inv = 1.f / (e0 + e1 + e2 + e3);
            float w0 = e0*inv, w1 = e1*inv, w2 = e2*inv, w3 = e3*inv;
            float at[8];
#pragma unroll
            for (int e = 0; e < 8; ++e)
                at[e] = cx[e].x*w0 + cx[e].y*w1 + cx[e].z*w2 + cx[e].w*w3;
#pragma unroll
            for (int p = 0; p < 4; ++p)
                attnu[mt2][nt][p] = pk_f16(at[2*p], at[2*p+1]);
        }
    }

    // GEMM2: out[256][64px] = rw[256][64] @ attn[64][64px], 4 M-passes
    float* Ob = out + (size_t)b * CIN * HW;
    for (int pm = 0; pm < 4; ++pm) {
        f32x4 oacc[4][4];
#pragma unroll
        for (int m = 0; m < 4; ++m)
#pragma unroll
            for (int n = 0; n < 4; ++n) oacc[m][n] = (f32x4){0.f, 0.f, 0.f, 0.f};
#pragma unroll
        for (int kc2 = 0; kc2 < 2; ++kc2) {
            f16x8 bfr2[4];
#pragma unroll
            for (int nt = 0; nt < 4; ++nt) {
                union { f16x8 v; unsigned u[4]; } c;
#pragma unroll
                for (int p = 0; p < 4; ++p) c.u[p] = attnu[kc2][nt][p];
                bfr2[nt] = c.v;
            }
#pragma unroll
            for (int mt = 0; mt < 4; ++mt) {
                f16x8 afr2 = *(const f16x8*)(rwf +
                    (size_t)((((pm*4 + mt)*2 + kc2)*64 + lane))*8);
#pragma unroll
                for (int nt = 0; nt < 4; ++nt)
                    oacc[mt][nt] = __builtin_amdgcn_mfma_f32_16x16x32_f16(
                        afr2, bfr2[nt], oacc[mt][nt], 0, 0, 0);
            }
        }
#pragma unroll
        for (int mt = 0; mt < 4; ++mt) {
            int o0 = (pm*4 + mt)*16 + kb*4;
            float4 rb4 = *(const float4*)(rb_ + o0);
#pragma unroll
            for (int nt = 0; nt < 4; ++nt) {
                int px = px0 + nt*16 + col;
                float* op = Ob + (size_t)o0 * HW + px;
                op[0]              = oacc[mt][nt][0] + rb4.x;
                op[HW]             = oacc[mt][nt][1] + rb4.y;
                op[2*(size_t)HW]   = oacc[mt][nt][2] + rb4.z;
                op[3*(size_t)HW]   = oacc[mt][nt][3] + rb4.w;
            }
        }
    }
}

// ---------------------------------------------------------------------------
extern "C" void kernel_launch(void* const* d_in, const int* in_sizes, int n_in,
                              void* d_out, int out_size, void* d_ws, size_t ws_size,
                              hipStream_t stream) {
    const float* target = (const float*)d_in[0];
    const float* input  = (const float*)d_in[1];
    const float* kw = (const float*)d_in[2];
    const float* kb = (const float*)d_in[3];
    const float* qw = (const float*)d_in[4];
    const float* qb = (const float*)d_in[5];
    const float* vw = (const float*)d_in[6];
    const float* vb = (const float*)d_in[7];
    const float* rw = (const float*)d_in[8];
    const float* rb = (const float*)d_in[9];
    float* out = (float*)d_out;
    float* ws  = (float*)d_ws;

    f16*      wkvf = (f16*)(ws + WS_WKVF);
    f16*      qwf  = (f16*)(ws + WS_QWF);
    f16*      rwf  = (f16*)(ws + WS_RWF);
    unsigned* kp   = (unsigned*)(ws + WS_KP);
    unsigned* vp   = (unsigned*)(ws + WS_VP);
    float*    part = ws + WS_PART;
    float*    ctx  = ws + WS_CTX;

    hipLaunchKernelGGL(prepack, dim3(32), dim3(256), 0, stream,
                       kw, vw, qw, rw, wkvf, qwf, rwf);
    hipLaunchKernelGGL(proj_kv_mfma, dim3(BATCH * HW / 128), dim3(256), 0, stream,
                       input, wkvf, kb, vb, kp, vp);
    hipLaunchKernelGGL(ctx_partial, dim3(BATCH * HEADS * 16), dim3(256), 0, stream,
                       kp, vp, part);
    hipLaunchKernelGGL(ctx_final, dim3(BATCH), dim3(256), 0, stream,
                       part, ctx);
    hipLaunchKernelGGL(fused_mfma, dim3(BATCH * HW / 256), dim3(256), 0, stream,
                       target, qwf, qb, ctx, rwf, rb, out);
}